// Round 8
// baseline (170.903 us; speedup 1.0000x reference)
//
#include <hip/hip_runtime.h>
#include <stdint.h>

// ---------------------------------------------------------------------------
// Sampler: scaled = logits/temp ; kth = 50th largest per row ; mask < kth ;
// token = argmax(scaled_masked + gumbel) with JAX threefry2x32 key (0,42).
// Output dtype: int32 (jax.random.categorical returns int32).
//
// JAX PRNG mode: jax_threefry_partitionable=True (modern default) ->
// bits[i] = o0^o1 of threefry((0,42),(0,i)). Legacy split-iota mode kept
// behind the flag as the fallback fork if validation mismatches.
// ---------------------------------------------------------------------------
#define JAX_PARTITIONABLE 1

#define CPB 64            // chunks (blocks) per row in the sampling kernel

// ----------------------------- threefry2x32 --------------------------------
__device__ __forceinline__ void tf2x32(uint32_t c0, uint32_t c1,
                                       uint32_t& o0, uint32_t& o1) {
  const uint32_t ks0 = 0u;
  const uint32_t ks1 = 42u;
  const uint32_t ks2 = 0x1BD11BDAu ^ ks0 ^ ks1;  // 0x1BD11BF0
  uint32_t x0 = c0 + ks0;
  uint32_t x1 = c1 + ks1;
#define TF_ROUND(r) { x0 += x1; x1 = (x1 << (r)) | (x1 >> (32 - (r))); x1 ^= x0; }
  TF_ROUND(13) TF_ROUND(15) TF_ROUND(26) TF_ROUND(6)
  x0 += ks1; x1 += ks2 + 1u;
  TF_ROUND(17) TF_ROUND(29) TF_ROUND(16) TF_ROUND(24)
  x0 += ks2; x1 += ks0 + 2u;
  TF_ROUND(13) TF_ROUND(15) TF_ROUND(26) TF_ROUND(6)
  x0 += ks0; x1 += ks1 + 3u;
  TF_ROUND(17) TF_ROUND(29) TF_ROUND(16) TF_ROUND(24)
  x0 += ks1; x1 += ks2 + 4u;
  TF_ROUND(13) TF_ROUND(15) TF_ROUND(26) TF_ROUND(6)
  x0 += ks2; x1 += ks0 + 5u;
#undef TF_ROUND
  o0 = x0; o1 = x1;
}

__device__ __forceinline__ uint32_t jax_bits(uint32_t i, uint32_t half) {
#if JAX_PARTITIONABLE
  (void)half;
  uint32_t o0, o1;
  tf2x32(0u, i, o0, o1);        // 64-bit counter (hi=0, lo=i)
  return o0 ^ o1;               // 32-bit output XORs the two words
#else
  uint32_t o0, o1;
  if (i < half) { tf2x32(i, i + half, o0, o1); return o0; }
  else          { tf2x32(i - half, i, o0, o1); return o1; }
#endif
}

// uniform in [tiny, 1) then gumbel, exactly as jax.random.uniform/gumbel
__device__ __forceinline__ float gumbel_from_bits(uint32_t b) {
  float f = __uint_as_float((b >> 9) | 0x3F800000u) - 1.0f;  // [0,1)
  float u = f + 1.17549435e-38f;   // f==0 -> tiny, else f (fp32 exact)
  return -logf(-logf(u));
}

// monotone float -> uint key (ascending order preserved)
__device__ __forceinline__ uint32_t f2key(uint32_t bits) {
  return (bits & 0x80000000u) ? ~bits : (bits | 0x80000000u);
}

// ------------------- kernel 1: per-row kth-largest threshold ----------------
// One block per row. 3-pass radix select (12 + 12 + 8 bits) on raw logit keys
// (division by temp is monotone, so order statistics commute through it).
// Scan loops vectorized float4 (16B/lane) for memory-level parallelism at the
// low block count. Writes BOTH the raw kth logit (integer prefilter) and the
// scaled threshold kth = raw/temp (exact value the reference compares with).
__global__ __launch_bounds__(1024) void topk_thresh_kernel(
    const float* __restrict__ logits, const float* __restrict__ temps,
    const int* __restrict__ topk_p, float* __restrict__ thr,
    float* __restrict__ thr_raw, int V) {
  const int row = blockIdx.x;
  const float* lrow = logits + (size_t)row * V;
  const float4* lrow4 = (const float4*)lrow;
  const int n4 = V >> 2;
  const int tid = threadIdx.x;

  __shared__ uint32_t hist[4096];
  __shared__ uint32_t gsum[64];
  __shared__ uint32_t s_sel, s_rem;

  int kk = *topk_p;

  // ---- pass A: top 12 bits ----
  for (int i = tid; i < 4096; i += blockDim.x) hist[i] = 0;
  __syncthreads();
  for (int i = tid; i < n4; i += blockDim.x) {
    float4 l4 = lrow4[i];
    float lv[4] = {l4.x, l4.y, l4.z, l4.w};
#pragma unroll
    for (int j = 0; j < 4; ++j) {
      uint32_t key = f2key(__float_as_uint(lv[j]));
      atomicAdd(&hist[key >> 20], 1u);
    }
  }
  for (int v = (n4 << 2) + tid; v < V; v += blockDim.x) {
    uint32_t key = f2key(__float_as_uint(lrow[v]));
    atomicAdd(&hist[key >> 20], 1u);
  }
  __syncthreads();
  if (tid < 64) {
    uint32_t g = 0;
    for (int j = 0; j < 64; ++j) g += hist[tid * 64 + j];
    gsum[tid] = g;
  }
  __syncthreads();
  if (tid == 0) {
    uint32_t cum = 0; int g = 63;
    while (g > 0 && cum + gsum[g] < (uint32_t)kk) { cum += gsum[g]; --g; }
    int b = g * 64 + 63;
    while (b > g * 64 && cum + hist[b] < (uint32_t)kk) { cum += hist[b]; --b; }
    s_sel = (uint32_t)b;
    s_rem = (uint32_t)kk - cum;
  }
  __syncthreads();
  const uint32_t bin12 = s_sel;
  kk = (int)s_rem;
  __syncthreads();

  // ---- pass B: bits 19:8 within bin12 ----
  for (int i = tid; i < 4096; i += blockDim.x) hist[i] = 0;
  __syncthreads();
  for (int i = tid; i < n4; i += blockDim.x) {
    float4 l4 = lrow4[i];
    float lv[4] = {l4.x, l4.y, l4.z, l4.w};
#pragma unroll
    for (int j = 0; j < 4; ++j) {
      uint32_t key = f2key(__float_as_uint(lv[j]));
      if ((key >> 20) == bin12) atomicAdd(&hist[(key >> 8) & 0xFFFu], 1u);
    }
  }
  for (int v = (n4 << 2) + tid; v < V; v += blockDim.x) {
    uint32_t key = f2key(__float_as_uint(lrow[v]));
    if ((key >> 20) == bin12) atomicAdd(&hist[(key >> 8) & 0xFFFu], 1u);
  }
  __syncthreads();
  if (tid < 64) {
    uint32_t g = 0;
    for (int j = 0; j < 64; ++j) g += hist[tid * 64 + j];
    gsum[tid] = g;
  }
  __syncthreads();
  if (tid == 0) {
    uint32_t cum = 0; int g = 63;
    while (g > 0 && cum + gsum[g] < (uint32_t)kk) { cum += gsum[g]; --g; }
    int b = g * 64 + 63;
    while (b > g * 64 && cum + hist[b] < (uint32_t)kk) { cum += hist[b]; --b; }
    s_sel = (uint32_t)b;
    s_rem = (uint32_t)kk - cum;
  }
  __syncthreads();
  const uint32_t bin24 = (bin12 << 12) | s_sel;
  kk = (int)s_rem;
  __syncthreads();

  // ---- pass C: low 8 bits within bin24 ----
  for (int i = tid; i < 256; i += blockDim.x) hist[i] = 0;
  __syncthreads();
  for (int i = tid; i < n4; i += blockDim.x) {
    float4 l4 = lrow4[i];
    float lv[4] = {l4.x, l4.y, l4.z, l4.w};
#pragma unroll
    for (int j = 0; j < 4; ++j) {
      uint32_t key = f2key(__float_as_uint(lv[j]));
      if ((key >> 8) == bin24) atomicAdd(&hist[key & 0xFFu], 1u);
    }
  }
  for (int v = (n4 << 2) + tid; v < V; v += blockDim.x) {
    uint32_t key = f2key(__float_as_uint(lrow[v]));
    if ((key >> 8) == bin24) atomicAdd(&hist[key & 0xFFu], 1u);
  }
  __syncthreads();
  if (tid == 0) {
    uint32_t cum = 0; int b = 255;
    while (b > 0 && cum + hist[b] < (uint32_t)kk) { cum += hist[b]; --b; }
    uint32_t key = (bin24 << 8) | (uint32_t)b;
    uint32_t fbits = (key & 0x80000000u) ? (key & 0x7FFFFFFFu) : ~key;
    float kth_logit = __uint_as_float(fbits);
    thr_raw[row] = kth_logit;
    thr[row] = kth_logit / temps[row];   // identical IEEE op to reference
  }
}

// ------------- kernel 2: gumbel + masked argmax (per-chunk partial) ---------
// Fast path: integer key-compare against the raw kth key. Only elements at or
// above (or within a conservative 64-key band below, where division rounding
// could still equalize) do the exact division + mask check + threefry gumbel.
__global__ __launch_bounds__(256) void sample_partial_kernel(
    const float* __restrict__ logits, const float* __restrict__ temps,
    const float* __restrict__ thr, const float* __restrict__ thr_raw,
    float* __restrict__ pval, int* __restrict__ pidx, int V, uint32_t half) {
  const int row = blockIdx.y;
  const int chunk = blockIdx.x;
  const int chunkElems = V / CPB;              // 2000 for V=128000, CPB=64
  const int base = chunk * chunkElems;
  const float* lrow = logits + (size_t)row * V;
  const float temp = temps[row];
  const float kth = thr[row];
  const uint32_t kthkey = f2key(__float_as_uint(thr_raw[row]));
  const uint32_t rowBase = (uint32_t)(row * V);

  float best = -INFINITY;
  int bestIdx = 0x7FFFFFFF;

  const int n4 = chunkElems / 4;
  const float4* lrow4 = (const float4*)(lrow + base);
  for (int i = threadIdx.x; i < n4; i += blockDim.x) {
    float4 l4 = lrow4[i];
    float lv[4] = {l4.x, l4.y, l4.z, l4.w};
    const int v0 = base + i * 4;
#pragma unroll
    for (int j = 0; j < 4; ++j) {
      uint32_t key = f2key(__float_as_uint(lv[j]));
      // definitely-masked fast exit (99.96% of elements): >64 keys below kth
      if (key < kthkey && (kthkey - key) > 64u) continue;
      float s = lv[j] / temp;                  // same IEEE div as reference
      if (s < kth) continue;                   // exact reference mask
      uint32_t gi = rowBase + (uint32_t)(v0 + j);
      float g = gumbel_from_bits(jax_bits(gi, half));
      float val = s + g;
      int idx = v0 + j;
      if (val > best || (val == best && idx < bestIdx)) { best = val; bestIdx = idx; }
    }
  }

  // wave reduce (64 lanes), first-index tie-break
#pragma unroll
  for (int off = 32; off > 0; off >>= 1) {
    float ov = __shfl_down(best, off, 64);
    int oi = __shfl_down(bestIdx, off, 64);
    if (ov > best || (ov == best && oi < bestIdx)) { best = ov; bestIdx = oi; }
  }
  __shared__ float swv[4];
  __shared__ int swi[4];
  const int wid = threadIdx.x >> 6;
  const int lane = threadIdx.x & 63;
  if (lane == 0) { swv[wid] = best; swi[wid] = bestIdx; }
  __syncthreads();
  if (threadIdx.x == 0) {
    const int nw = (int)(blockDim.x >> 6);
    for (int w = 1; w < nw; ++w) {
      if (swv[w] > best || (swv[w] == best && swi[w] < bestIdx)) {
        best = swv[w]; bestIdx = swi[w];
      }
    }
    const int slot = row * CPB + chunk;
    pval[slot] = best;
    pidx[slot] = bestIdx;
  }
}

// ----------------- kernel 3: final reduce over CPB partials -----------------
__global__ void reduce_kernel(const float* __restrict__ pval,
                              const int* __restrict__ pidx,
                              int* __restrict__ out, int B) {
  const int r = blockIdx.x * blockDim.x + threadIdx.x;
  if (r >= B) return;
  float best = -INFINITY;
  int bestIdx = 0x7FFFFFFF;
  for (int c = 0; c < CPB; ++c) {
    float v = pval[r * CPB + c];
    int i = pidx[r * CPB + c];
    if (v > best || (v == best && i < bestIdx)) { best = v; bestIdx = i; }
  }
  out[r] = bestIdx;   // int32 output, matching jax.random.categorical dtype
}

// ---------------------------------------------------------------------------
extern "C" void kernel_launch(void* const* d_in, const int* in_sizes, int n_in,
                              void* d_out, int out_size, void* d_ws, size_t ws_size,
                              hipStream_t stream) {
  const float* logits = (const float*)d_in[0];
  const float* temps  = (const float*)d_in[1];
  const int*   topk   = (const int*)d_in[2];
  const int B = in_sizes[1];
  const int V = in_sizes[0] / B;

  float* thr    = (float*)d_ws;              // B floats
  float* thrRaw = thr + B;                   // B floats
  float* pval   = thrRaw + B;                // B*CPB floats
  int*   pidx   = (int*)(pval + B * CPB);    // B*CPB ints
  const uint32_t half = (uint32_t)(((long long)B * (long long)V) / 2);

  topk_thresh_kernel<<<B, 1024, 0, stream>>>(logits, temps, topk, thr, thrRaw, V);
  dim3 g2(CPB, B);
  sample_partial_kernel<<<g2, 256, 0, stream>>>(logits, temps, thr, thrRaw,
                                                pval, pidx, V, half);
  reduce_kernel<<<(B + 127) / 128, 128, 0, stream>>>(pval, pidx, (int*)d_out, B);
}

// Round 11
// 159.279 us; speedup vs baseline: 1.0730x; 1.0730x over previous
//
#include <hip/hip_runtime.h>
#include <stdint.h>

// ---------------------------------------------------------------------------
// Sampler: scaled = logits/temp ; kth = 50th largest per row ; mask < kth ;
// token = argmax(scaled + gumbel) over survivors, JAX threefry key (0,42).
// VALIDATED R8: partitionable threefry (o0^o1), int32 output, absmax 0.0.
//
// R9 restructure: full-chip radix select.
//  zero -> hist(SPA blocks/row, LDS hist + global merge) -> selbin(top 12 bits)
//  -> compact(kth-bin candidates) -> selfin(low 20 bits among candidates)
//  -> sample(prefiltered gumbel argmax, CPB chunks/row) -> reduce
// ---------------------------------------------------------------------------
#define JAX_PARTITIONABLE 1
#define SPA   8      // scan splits per row (hist & compact)
#define MAXC  4096   // candidate capacity per row (expected ~15-60 used)
#define CPB   16     // chunks per row in sampling kernel

// ----------------------------- threefry2x32 --------------------------------
__device__ __forceinline__ void tf2x32(uint32_t c0, uint32_t c1,
                                       uint32_t& o0, uint32_t& o1) {
  const uint32_t ks0 = 0u;
  const uint32_t ks1 = 42u;
  const uint32_t ks2 = 0x1BD11BDAu ^ ks0 ^ ks1;
  uint32_t x0 = c0 + ks0;
  uint32_t x1 = c1 + ks1;
#define TF_ROUND(r) { x0 += x1; x1 = (x1 << (r)) | (x1 >> (32 - (r))); x1 ^= x0; }
  TF_ROUND(13) TF_ROUND(15) TF_ROUND(26) TF_ROUND(6)
  x0 += ks1; x1 += ks2 + 1u;
  TF_ROUND(17) TF_ROUND(29) TF_ROUND(16) TF_ROUND(24)
  x0 += ks2; x1 += ks0 + 2u;
  TF_ROUND(13) TF_ROUND(15) TF_ROUND(26) TF_ROUND(6)
  x0 += ks0; x1 += ks1 + 3u;
  TF_ROUND(17) TF_ROUND(29) TF_ROUND(16) TF_ROUND(24)
  x0 += ks1; x1 += ks2 + 4u;
  TF_ROUND(13) TF_ROUND(15) TF_ROUND(26) TF_ROUND(6)
  x0 += ks2; x1 += ks0 + 5u;
#undef TF_ROUND
  o0 = x0; o1 = x1;
}

__device__ __forceinline__ uint32_t jax_bits(uint32_t i, uint32_t half) {
#if JAX_PARTITIONABLE
  (void)half;
  uint32_t o0, o1;
  tf2x32(0u, i, o0, o1);
  return o0 ^ o1;
#else
  uint32_t o0, o1;
  if (i < half) { tf2x32(i, i + half, o0, o1); return o0; }
  else          { tf2x32(i - half, i, o0, o1); return o1; }
#endif
}

__device__ __forceinline__ float gumbel_from_bits(uint32_t b) {
  float f = __uint_as_float((b >> 9) | 0x3F800000u) - 1.0f;  // [0,1)
  float u = f + 1.17549435e-38f;
  return -logf(-logf(u));
}

// monotone float -> uint key (ascending order preserved)
__device__ __forceinline__ uint32_t f2key(uint32_t bits) {
  return (bits & 0x80000000u) ? ~bits : (bits | 0x80000000u);
}

// --------------------------- zero workspace --------------------------------
__global__ void zero_kernel(uint32_t* __restrict__ p, int n) {
  int i = blockIdx.x * blockDim.x + threadIdx.x;
  const int stride = gridDim.x * blockDim.x;
  for (; i < n; i += stride) p[i] = 0u;
}

// ---------------- k1a: per-row 4096-bin histogram (full chip) ---------------
__global__ __launch_bounds__(256) void hist_kernel(
    const float* __restrict__ logits, uint32_t* __restrict__ ghist, int V) {
  const int row = blockIdx.y, slice = blockIdx.x;
  const float* lrow = logits + (size_t)row * V;
  const float4* l4p = (const float4*)lrow;
  const int n4tot = V >> 2;
  const int s4 = slice * n4tot / SPA;
  const int e4 = (slice + 1) * n4tot / SPA;

  __shared__ uint32_t lh[4096];
  for (int i = threadIdx.x; i < 4096; i += 256) lh[i] = 0;
  __syncthreads();

  for (int i = s4 + threadIdx.x; i < e4; i += 256) {
    float4 l4 = l4p[i];
    float lv[4] = {l4.x, l4.y, l4.z, l4.w};
#pragma unroll
    for (int j = 0; j < 4; ++j)
      atomicAdd(&lh[f2key(__float_as_uint(lv[j])) >> 20], 1u);
  }
  if (slice == 0) {  // scalar tail (V % 4)
    for (int v = (n4tot << 2) + threadIdx.x; v < V; v += 256)
      atomicAdd(&lh[f2key(__float_as_uint(lrow[v])) >> 20], 1u);
  }
  __syncthreads();

  uint32_t* gh = ghist + (size_t)row * 4096;
  for (int b = threadIdx.x; b < 4096; b += 256)
    if (lh[b]) atomicAdd(&gh[b], lh[b]);
}

// ---------------- k1b: pick top-12-bit bin of the kth element ---------------
__global__ __launch_bounds__(256) void selbin_kernel(
    const uint32_t* __restrict__ ghist, const int* __restrict__ topk_p,
    uint32_t* __restrict__ bin12, uint32_t* __restrict__ remk) {
  const int row = blockIdx.x;
  const uint32_t* gh = ghist + (size_t)row * 4096;
  __shared__ uint32_t lh[4096];
  __shared__ uint32_t gsum[64];
  for (int i = threadIdx.x; i < 4096; i += 256) lh[i] = gh[i];
  __syncthreads();
  if (threadIdx.x < 64) {
    uint32_t g = 0;
    for (int j = 0; j < 64; ++j) g += lh[threadIdx.x * 64 + j];
    gsum[threadIdx.x] = g;
  }
  __syncthreads();
  if (threadIdx.x == 0) {
    const uint32_t kk = (uint32_t)(*topk_p);
    uint32_t cum = 0; int g = 63;
    while (g > 0 && cum + gsum[g] < kk) { cum += gsum[g]; --g; }
    int b = g * 64 + 63;
    while (b > g * 64 && cum + lh[b] < kk) { cum += lh[b]; --b; }
    bin12[row] = (uint32_t)b;
    remk[row] = kk - cum;
  }
}

// ---------------- k1c: compact candidates in the kth bin --------------------
__global__ __launch_bounds__(256) void compact_kernel(
    const float* __restrict__ logits, const uint32_t* __restrict__ bin12,
    uint32_t* __restrict__ candcnt, uint32_t* __restrict__ cand, int V) {
  const int row = blockIdx.y, slice = blockIdx.x;
  const uint32_t b12 = bin12[row];
  const float* lrow = logits + (size_t)row * V;
  const float4* l4p = (const float4*)lrow;
  const int n4tot = V >> 2;
  const int s4 = slice * n4tot / SPA;
  const int e4 = (slice + 1) * n4tot / SPA;

  for (int i = s4 + threadIdx.x; i < e4; i += 256) {
    float4 l4 = l4p[i];
    float lv[4] = {l4.x, l4.y, l4.z, l4.w};
#pragma unroll
    for (int j = 0; j < 4; ++j) {
      uint32_t key = f2key(__float_as_uint(lv[j]));
      if ((key >> 20) == b12) {
        uint32_t p = atomicAdd(&candcnt[row], 1u);
        if (p < MAXC) cand[(size_t)row * MAXC + p] = key;
      }
    }
  }
  if (slice == 0) {
    for (int v = (n4tot << 2) + threadIdx.x; v < V; v += 256) {
      uint32_t key = f2key(__float_as_uint(lrow[v]));
      if ((key >> 20) == b12) {
        uint32_t p = atomicAdd(&candcnt[row], 1u);
        if (p < MAXC) cand[(size_t)row * MAXC + p] = key;
      }
    }
  }
}

// ---------------- k1d: select low 20 bits among candidates ------------------
__global__ __launch_bounds__(256) void selfin_kernel(
    const uint32_t* __restrict__ cand, const uint32_t* __restrict__ candcnt,
    const uint32_t* __restrict__ bin12, const uint32_t* __restrict__ remk,
    const float* __restrict__ temps, float* __restrict__ thr,
    float* __restrict__ thrRaw) {
  const int row = blockIdx.x;
  const uint32_t n = min(candcnt[row], (uint32_t)MAXC);
  const uint32_t* cr = cand + (size_t)row * MAXC;
  __shared__ uint32_t lh[4096];
  __shared__ uint32_t gsum[64];
  __shared__ uint32_t s_sel, s_rem;

  // pass 1: bits 19:8 (4096 bins)
  for (int i = threadIdx.x; i < 4096; i += 256) lh[i] = 0;
  __syncthreads();
  for (uint32_t i = threadIdx.x; i < n; i += 256)
    atomicAdd(&lh[(cr[i] >> 8) & 0xFFFu], 1u);
  __syncthreads();
  if (threadIdx.x < 64) {
    uint32_t g = 0;
    for (int j = 0; j < 64; ++j) g += lh[threadIdx.x * 64 + j];
    gsum[threadIdx.x] = g;
  }
  __syncthreads();
  if (threadIdx.x == 0) {
    uint32_t kk = remk[row], cum = 0; int g = 63;
    while (g > 0 && cum + gsum[g] < kk) { cum += gsum[g]; --g; }
    int b = g * 64 + 63;
    while (b > g * 64 && cum + lh[b] < kk) { cum += lh[b]; --b; }
    s_sel = (uint32_t)b;
    s_rem = kk - cum;
  }
  __syncthreads();
  const uint32_t sel12 = s_sel;
  const uint32_t kk2 = s_rem;
  __syncthreads();

  // pass 2: low 8 bits among candidates in (bin12, sel12)
  for (int i = threadIdx.x; i < 256; i += 256) lh[i] = 0;
  __syncthreads();
  for (uint32_t i = threadIdx.x; i < n; i += 256) {
    uint32_t k = cr[i];
    if (((k >> 8) & 0xFFFu) == sel12) atomicAdd(&lh[k & 0xFFu], 1u);
  }
  __syncthreads();
  if (threadIdx.x == 0) {
    uint32_t cum = 0; int b = 255;
    while (b > 0 && cum + lh[b] < kk2) { cum += lh[b]; --b; }
    uint32_t key = (bin12[row] << 20) | (sel12 << 8) | (uint32_t)b;
    uint32_t fbits = (key & 0x80000000u) ? (key & 0x7FFFFFFFu) : ~key;
    float kraw = __uint_as_float(fbits);
    thrRaw[row] = kraw;
    thr[row] = kraw / temps[row];   // identical IEEE op to reference
  }
}

// ------------- k2: gumbel + masked argmax (per-chunk partial) ---------------
__global__ __launch_bounds__(256) void sample_partial_kernel(
    const float* __restrict__ logits, const float* __restrict__ temps,
    const float* __restrict__ thr, const float* __restrict__ thr_raw,
    float* __restrict__ pval, int* __restrict__ pidx, int V, uint32_t half) {
  const int row = blockIdx.y;
  const int chunk = blockIdx.x;
  const float* lrow = logits + (size_t)row * V;
  const float4* l4p = (const float4*)lrow;
  const float temp = temps[row];
  const float kth = thr[row];
  const uint32_t kthkey = f2key(__float_as_uint(thr_raw[row]));
  const uint32_t rowBase = (uint32_t)(row * V);
  const int n4tot = V >> 2;
  const int s4 = chunk * n4tot / CPB;
  const int e4 = (chunk + 1) * n4tot / CPB;

  float best = -INFINITY;
  int bestIdx = 0x7FFFFFFF;

  for (int i = s4 + threadIdx.x; i < e4; i += 256) {
    float4 l4 = l4p[i];
    float lv[4] = {l4.x, l4.y, l4.z, l4.w};
    const int v0 = i * 4;
#pragma unroll
    for (int j = 0; j < 4; ++j) {
      uint32_t key = f2key(__float_as_uint(lv[j]));
      // definitely-masked fast exit: >64 ulp-keys below the raw kth key
      if (key < kthkey && (kthkey - key) > 64u) continue;
      float s = lv[j] / temp;                  // same IEEE div as reference
      if (s < kth) continue;                   // exact reference mask
      uint32_t gi = rowBase + (uint32_t)(v0 + j);
      float g = gumbel_from_bits(jax_bits(gi, half));
      float val = s + g;
      int idx = v0 + j;
      if (val > best || (val == best && idx < bestIdx)) { best = val; bestIdx = idx; }
    }
  }
  if (chunk == 0) {  // scalar tail
    for (int v = (n4tot << 2) + threadIdx.x; v < V; v += 256) {
      float lvv = lrow[v];
      uint32_t key = f2key(__float_as_uint(lvv));
      if (key < kthkey && (kthkey - key) > 64u) continue;
      float s = lvv / temp;
      if (s < kth) continue;
      float g = gumbel_from_bits(jax_bits(rowBase + (uint32_t)v, half));
      float val = s + g;
      if (val > best || (val == best && v < bestIdx)) { best = val; bestIdx = v; }
    }
  }

  // wave reduce (64 lanes), first-index tie-break
#pragma unroll
  for (int off = 32; off > 0; off >>= 1) {
    float ov = __shfl_down(best, off, 64);
    int oi = __shfl_down(bestIdx, off, 64);
    if (ov > best || (ov == best && oi < bestIdx)) { best = ov; bestIdx = oi; }
  }
  __shared__ float swv[4];
  __shared__ int swi[4];
  const int wid = threadIdx.x >> 6;
  const int lane = threadIdx.x & 63;
  if (lane == 0) { swv[wid] = best; swi[wid] = bestIdx; }
  __syncthreads();
  if (threadIdx.x == 0) {
    for (int w = 1; w < 4; ++w) {
      if (swv[w] > best || (swv[w] == best && swi[w] < bestIdx)) {
        best = swv[w]; bestIdx = swi[w];
      }
    }
    const int slot = row * CPB + chunk;
    pval[slot] = best;
    pidx[slot] = bestIdx;
  }
}

// ----------------- k3: final reduce over CPB partials -----------------------
__global__ void reduce_kernel(const float* __restrict__ pval,
                              const int* __restrict__ pidx,
                              int* __restrict__ out, int B) {
  const int r = blockIdx.x * blockDim.x + threadIdx.x;
  if (r >= B) return;
  float best = -INFINITY;
  int bestIdx = 0x7FFFFFFF;
  for (int c = 0; c < CPB; ++c) {
    float v = pval[r * CPB + c];
    int i = pidx[r * CPB + c];
    if (v > best || (v == best && i < bestIdx)) { best = v; bestIdx = i; }
  }
  out[r] = bestIdx;
}

// ---------------------------------------------------------------------------
extern "C" void kernel_launch(void* const* d_in, const int* in_sizes, int n_in,
                              void* d_out, int out_size, void* d_ws, size_t ws_size,
                              hipStream_t stream) {
  const float* logits = (const float*)d_in[0];
  const float* temps  = (const float*)d_in[1];
  const int*   topk   = (const int*)d_in[2];
  const int B = in_sizes[1];
  const int V = in_sizes[0] / B;

  // workspace layout (4-byte words); candcnt..ghist contiguous for one zero
  float*    thr     = (float*)d_ws;                    // B
  float*    thrRaw  = thr + B;                         // B
  uint32_t* bin12   = (uint32_t*)(thrRaw + B);         // B
  uint32_t* remk    = bin12 + B;                       // B
  float*    pval    = (float*)(remk + B);              // B*CPB
  int*      pidx    = (int*)(pval + (size_t)B * CPB);  // B*CPB
  uint32_t* candcnt = (uint32_t*)(pidx + (size_t)B * CPB);  // B
  uint32_t* ghist   = candcnt + B;                     // B*4096
  uint32_t* cand    = ghist;  // alias: ghist dead after selbin, reused as cand

  const uint32_t half = (uint32_t)(((long long)B * (long long)V) / 2);
  const int nzero = B + B * 4096;  // candcnt + ghist

  zero_kernel<<<2048, 256, 0, stream>>>(candcnt, nzero);
  hist_kernel<<<dim3(SPA, B), 256, 0, stream>>>(logits, ghist, V);
  selbin_kernel<<<B, 256, 0, stream>>>(ghist, topk, bin12, remk);
  compact_kernel<<<dim3(SPA, B), 256, 0, stream>>>(logits, bin12, candcnt, cand, V);
  selfin_kernel<<<B, 256, 0, stream>>>(cand, candcnt, bin12, remk, temps, thr, thrRaw);
  sample_partial_kernel<<<dim3(CPB, B), 256, 0, stream>>>(logits, temps, thr, thrRaw,
                                                          pval, pidx, V, half);
  reduce_kernel<<<(B + 127) / 128, 128, 0, stream>>>(pval, pidx, (int*)d_out, B);
}

// Round 14
// 153.508 us; speedup vs baseline: 1.1133x; 1.0376x over previous
//
#include <hip/hip_runtime.h>
#include <stdint.h>

// ---------------------------------------------------------------------------
// Sampler: scaled = logits/temp ; kth = 50th largest per row ; mask < kth ;
// token = argmax(scaled + gumbel) over survivors, JAX threefry key (0,42).
// VALIDATED R8/R11: partitionable threefry (o0^o1), int32 output, radix-select
// (hist->selbin->compact->selfin) — absmax 0.0.
//
// R12: remove the 3rd full scan. compact stores (key,idx) for all elements
// with key >= bin12_edge-64 (superset of survivors, ~100-300/row); finalize
// does selfin + reference-exact mask + gumbel argmax over candidates only.
//  zero -> hist -> selbin -> compact(key,idx) -> finalize
// ---------------------------------------------------------------------------
#define SPA   8      // scan splits per row (hist & compact)
#define MAXC  4096   // candidate capacity per row (expected ~100-300 used)

// ----------------------------- threefry2x32 --------------------------------
__device__ __forceinline__ void tf2x32(uint32_t c0, uint32_t c1,
                                       uint32_t& o0, uint32_t& o1) {
  const uint32_t ks0 = 0u;
  const uint32_t ks1 = 42u;
  const uint32_t ks2 = 0x1BD11BDAu ^ ks0 ^ ks1;
  uint32_t x0 = c0 + ks0;
  uint32_t x1 = c1 + ks1;
#define TF_ROUND(r) { x0 += x1; x1 = (x1 << (r)) | (x1 >> (32 - (r))); x1 ^= x0; }
  TF_ROUND(13) TF_ROUND(15) TF_ROUND(26) TF_ROUND(6)
  x0 += ks1; x1 += ks2 + 1u;
  TF_ROUND(17) TF_ROUND(29) TF_ROUND(16) TF_ROUND(24)
  x0 += ks2; x1 += ks0 + 2u;
  TF_ROUND(13) TF_ROUND(15) TF_ROUND(26) TF_ROUND(6)
  x0 += ks0; x1 += ks1 + 3u;
  TF_ROUND(17) TF_ROUND(29) TF_ROUND(16) TF_ROUND(24)
  x0 += ks1; x1 += ks2 + 4u;
  TF_ROUND(13) TF_ROUND(15) TF_ROUND(26) TF_ROUND(6)
  x0 += ks2; x1 += ks0 + 5u;
#undef TF_ROUND
  o0 = x0; o1 = x1;
}

// partitionable mode (VALIDATED): bits[i] = o0^o1 of threefry((0,42),(0,i))
__device__ __forceinline__ uint32_t jax_bits(uint32_t i) {
  uint32_t o0, o1;
  tf2x32(0u, i, o0, o1);
  return o0 ^ o1;
}

__device__ __forceinline__ float gumbel_from_bits(uint32_t b) {
  float f = __uint_as_float((b >> 9) | 0x3F800000u) - 1.0f;  // [0,1)
  float u = f + 1.17549435e-38f;
  return -logf(-logf(u));
}

// monotone float <-> uint key (ascending order preserved)
__device__ __forceinline__ uint32_t f2key(uint32_t bits) {
  return (bits & 0x80000000u) ? ~bits : (bits | 0x80000000u);
}
__device__ __forceinline__ float key2f(uint32_t key) {
  uint32_t fb = (key & 0x80000000u) ? (key & 0x7FFFFFFFu) : ~key;
  return __uint_as_float(fb);
}

// --------------------------- zero workspace --------------------------------
__global__ void zero_kernel(uint32_t* __restrict__ p, int n) {
  int i = blockIdx.x * blockDim.x + threadIdx.x;
  const int stride = gridDim.x * blockDim.x;
  for (; i < n; i += stride) p[i] = 0u;
}

// ---------------- k1a: per-row 4096-bin histogram (full chip) ---------------
__global__ __launch_bounds__(256) void hist_kernel(
    const float* __restrict__ logits, uint32_t* __restrict__ ghist, int V) {
  const int row = blockIdx.y, slice = blockIdx.x;
  const float* lrow = logits + (size_t)row * V;
  const float4* l4p = (const float4*)lrow;
  const int n4tot = V >> 2;
  const int s4 = slice * n4tot / SPA;
  const int e4 = (slice + 1) * n4tot / SPA;

  __shared__ uint32_t lh[4096];
  for (int i = threadIdx.x; i < 4096; i += 256) lh[i] = 0;
  __syncthreads();

  for (int i = s4 + threadIdx.x; i < e4; i += 256) {
    float4 l4 = l4p[i];
    float lv[4] = {l4.x, l4.y, l4.z, l4.w};
#pragma unroll
    for (int j = 0; j < 4; ++j)
      atomicAdd(&lh[f2key(__float_as_uint(lv[j])) >> 20], 1u);
  }
  if (slice == 0) {  // scalar tail (V % 4)
    for (int v = (n4tot << 2) + threadIdx.x; v < V; v += 256)
      atomicAdd(&lh[f2key(__float_as_uint(lrow[v])) >> 20], 1u);
  }
  __syncthreads();

  uint32_t* gh = ghist + (size_t)row * 4096;
  for (int b = threadIdx.x; b < 4096; b += 256)
    if (lh[b]) atomicAdd(&gh[b], lh[b]);   // sparse: most bins empty
}

// ---------------- k1b: pick top-12-bit bin of the kth element ---------------
__global__ __launch_bounds__(256) void selbin_kernel(
    const uint32_t* __restrict__ ghist, const int* __restrict__ topk_p,
    uint32_t* __restrict__ bin12, uint32_t* __restrict__ remk) {
  const int row = blockIdx.x;
  const uint32_t* gh = ghist + (size_t)row * 4096;
  __shared__ uint32_t lh[4096];
  __shared__ uint32_t gsum[64];
  for (int i = threadIdx.x; i < 4096; i += 256) lh[i] = gh[i];
  __syncthreads();
  if (threadIdx.x < 64) {
    uint32_t g = 0;
    for (int j = 0; j < 64; ++j) g += lh[threadIdx.x * 64 + j];
    gsum[threadIdx.x] = g;
  }
  __syncthreads();
  if (threadIdx.x == 0) {
    const uint32_t kk = (uint32_t)(*topk_p);
    uint32_t cum = 0; int g = 63;
    while (g > 0 && cum + gsum[g] < kk) { cum += gsum[g]; --g; }
    int b = g * 64 + 63;
    while (b > g * 64 && cum + lh[b] < kk) { cum += lh[b]; --b; }
    bin12[row] = (uint32_t)b;
    remk[row] = kk - cum;
  }
}

// ------- k1c: compact (key,idx) of all possible winners (full chip) ---------
// Superset condition: key >= bin12_lower_edge - 64 ulp-keys. Every reference
// survivor (s >= kth after division) lies in bin12 or above, or within a few
// ulps below the edge (division rounding); 64 is conservative.
__global__ __launch_bounds__(256) void compact_kernel(
    const float* __restrict__ logits, const uint32_t* __restrict__ bin12,
    uint32_t* __restrict__ candcnt, uint2* __restrict__ cand, int V) {
  const int row = blockIdx.y, slice = blockIdx.x;
  const uint32_t t = bin12[row] << 20;
  const uint32_t lo = (t >= 64u) ? t - 64u : 0u;
  const float* lrow = logits + (size_t)row * V;
  const float4* l4p = (const float4*)lrow;
  const int n4tot = V >> 2;
  const int s4 = slice * n4tot / SPA;
  const int e4 = (slice + 1) * n4tot / SPA;

  for (int i = s4 + threadIdx.x; i < e4; i += 256) {
    float4 l4 = l4p[i];
    float lv[4] = {l4.x, l4.y, l4.z, l4.w};
    const int v0 = i * 4;
#pragma unroll
    for (int j = 0; j < 4; ++j) {
      uint32_t key = f2key(__float_as_uint(lv[j]));
      if (key >= lo) {
        uint32_t p = atomicAdd(&candcnt[row], 1u);
        if (p < MAXC) cand[(size_t)row * MAXC + p] = make_uint2(key, (uint32_t)(v0 + j));
      }
    }
  }
  if (slice == 0) {  // scalar tail
    for (int v = (n4tot << 2) + threadIdx.x; v < V; v += 256) {
      uint32_t key = f2key(__float_as_uint(lrow[v]));
      if (key >= lo) {
        uint32_t p = atomicAdd(&candcnt[row], 1u);
        if (p < MAXC) cand[(size_t)row * MAXC + p] = make_uint2(key, (uint32_t)v);
      }
    }
  }
}

// ------- k2: selfin (exact kth) + exact-mask gumbel argmax per row ----------
__global__ __launch_bounds__(256) void finalize_kernel(
    const uint2* __restrict__ cand, const uint32_t* __restrict__ candcnt,
    const uint32_t* __restrict__ bin12, const uint32_t* __restrict__ remk,
    const float* __restrict__ temps, int* __restrict__ out, int V) {
  const int row = blockIdx.x;
  const uint32_t n = min(candcnt[row], (uint32_t)MAXC);
  const uint2* cr = cand + (size_t)row * MAXC;
  const uint32_t b12 = bin12[row];

  __shared__ uint32_t lh[4096];
  __shared__ uint32_t gsum[64];
  __shared__ uint32_t s_sel, s_rem;
  __shared__ float s_kth;

  // ---- pass 1: bits 19:8 among candidates in bin12 ----
  for (int i = threadIdx.x; i < 4096; i += 256) lh[i] = 0;
  __syncthreads();
  for (uint32_t i = threadIdx.x; i < n; i += 256) {
    uint32_t k = cr[i].x;
    if ((k >> 20) == b12) atomicAdd(&lh[(k >> 8) & 0xFFFu], 1u);
  }
  __syncthreads();
  if (threadIdx.x < 64) {
    uint32_t g = 0;
    for (int j = 0; j < 64; ++j) g += lh[threadIdx.x * 64 + j];
    gsum[threadIdx.x] = g;
  }
  __syncthreads();
  if (threadIdx.x == 0) {
    uint32_t kk = remk[row], cum = 0; int g = 63;
    while (g > 0 && cum + gsum[g] < kk) { cum += gsum[g]; --g; }
    int b = g * 64 + 63;
    while (b > g * 64 && cum + lh[b] < kk) { cum += lh[b]; --b; }
    s_sel = (uint32_t)b;
    s_rem = kk - cum;
  }
  __syncthreads();
  const uint32_t sel12 = s_sel;
  const uint32_t kk2 = s_rem;
  __syncthreads();

  // ---- pass 2: low 8 bits among candidates in (b12, sel12) ----
  for (int i = threadIdx.x; i < 256; i += 256) lh[i] = 0;
  __syncthreads();
  const uint32_t pre24 = (b12 << 12) | sel12;
  for (uint32_t i = threadIdx.x; i < n; i += 256) {
    uint32_t k = cr[i].x;
    if ((k >> 8) == pre24) atomicAdd(&lh[k & 0xFFu], 1u);
  }
  __syncthreads();
  if (threadIdx.x == 0) {
    uint32_t cum = 0; int b = 255;
    while (b > 0 && cum + lh[b] < kk2) { cum += lh[b]; --b; }
    uint32_t kthkey = (b12 << 20) | (sel12 << 8) | (uint32_t)b;
    s_kth = key2f(kthkey) / temps[row];   // identical IEEE op to reference
  }
  __syncthreads();

  // ---- pass 3: reference-exact mask + gumbel argmax over candidates ----
  const float temp = temps[row];
  const float kth = s_kth;
  const uint32_t rowBase = (uint32_t)(row * V);
  float best = -INFINITY;
  int bestIdx = 0x7FFFFFFF;
  for (uint32_t i = threadIdx.x; i < n; i += 256) {
    uint2 c = cr[i];
    float s = key2f(c.x) / temp;          // same IEEE div as reference
    if (s < kth) continue;                // exact reference mask
    float g = gumbel_from_bits(jax_bits(rowBase + c.y));
    float val = s + g;
    int idx = (int)c.y;
    if (val > best || (val == best && idx < bestIdx)) { best = val; bestIdx = idx; }
  }

  // wave reduce (64 lanes) + cross-wave, first-index tie-break
#pragma unroll
  for (int off = 32; off > 0; off >>= 1) {
    float ov = __shfl_down(best, off, 64);
    int oi = __shfl_down(bestIdx, off, 64);
    if (ov > best || (ov == best && oi < bestIdx)) { best = ov; bestIdx = oi; }
  }
  __shared__ float swv[4];
  __shared__ int swi[4];
  const int wid = threadIdx.x >> 6;
  const int lane = threadIdx.x & 63;
  if (lane == 0) { swv[wid] = best; swi[wid] = bestIdx; }
  __syncthreads();
  if (threadIdx.x == 0) {
    for (int w = 1; w < 4; ++w) {
      if (swv[w] > best || (swv[w] == best && swi[w] < bestIdx)) {
        best = swv[w]; bestIdx = swi[w];
      }
    }
    out[row] = bestIdx;   // int32 token
  }
}

// ---------------------------------------------------------------------------
extern "C" void kernel_launch(void* const* d_in, const int* in_sizes, int n_in,
                              void* d_out, int out_size, void* d_ws, size_t ws_size,
                              hipStream_t stream) {
  const float* logits = (const float*)d_in[0];
  const float* temps  = (const float*)d_in[1];
  const int*   topk   = (const int*)d_in[2];
  const int B = in_sizes[1];
  const int V = in_sizes[0] / B;

  // workspace layout; candcnt..ghist contiguous for the single zero pass
  uint2*    cand    = (uint2*)d_ws;                    // B*MAXC (8B each)
  uint32_t* bin12   = (uint32_t*)(cand + (size_t)B * MAXC);  // B
  uint32_t* remk    = bin12 + B;                       // B
  uint32_t* candcnt = remk + B;                        // B
  uint32_t* ghist   = candcnt + B;                     // B*4096

  const int nzero = B + B * 4096;  // candcnt + ghist

  zero_kernel<<<2048, 256, 0, stream>>>(candcnt, nzero);
  hist_kernel<<<dim3(SPA, B), 256, 0, stream>>>(logits, ghist, V);
  selbin_kernel<<<B, 256, 0, stream>>>(ghist, topk, bin12, remk);
  compact_kernel<<<dim3(SPA, B), 256, 0, stream>>>(logits, bin12, candcnt, cand, V);
  finalize_kernel<<<B, 256, 0, stream>>>(cand, candcnt, bin12, remk, temps,
                                         (int*)d_out, V);
}